// Round 8
// baseline (2011.075 us; speedup 1.0000x reference)
//
#include <hip/hip_runtime.h>
#include <hip/hip_bf16.h>
#include <math.h>

typedef __bf16 bf16;
typedef __bf16 bf16x8 __attribute__((ext_vector_type(8)));
typedef __bf16 bf16x4 __attribute__((ext_vector_type(4)));
typedef float f32x4 __attribute__((ext_vector_type(4)));
typedef unsigned int u32;
typedef u32 u32x4 __attribute__((ext_vector_type(4)));

#define NINP 400
#define HS   1000
#define HP   1024
#define B_   8
#define T_   256
#define NT   2048   /* B_*T_ */
#define M_   4096   /* 4 gates * HP */

#define HT_OFF   819200
#define CT_OFF   827200
#define AUX_OFF  835200

/* flat LDS layout (elems), per buffer: A-lo | A-hi | Hs(65 rows: boundary+64) */
#define ALO  0
#define AHI  4096
#define HSB  8192        /* boundary row at HSB..HSB+63; logical rows at HSB+64 */
#define BUFE 12352       /* 4096+4096+4160 elems = 24704 B per buffer */

typedef __attribute__((address_space(1))) const void gvoid;
typedef __attribute__((address_space(3))) void lvoid;

__device__ __forceinline__ void async_copy16(void* lds, const void* g) {
  __builtin_amdgcn_global_load_lds((gvoid*)g, (lvoid*)lds, 16, 0, 0);
}

__device__ __forceinline__ float sigm(float x) { return 1.0f / (1.0f + expf(-x)); }

// ---------------- repack kernels (fp32 inputs -> packed-m bf16) ----------------
// M-packing (unchanged): pm = (h>>5)*128 + ((h>>4)&1)*64 + g*16 + (h&15).
// W layout: k < KH -> tap0 (shifted input), k >= KH -> tap1.

__global__ void repack_w1(const float* __restrict__ w1, bf16* __restrict__ W1q) {
  int idx = blockIdx.x * 256 + threadIdx.x;           // 4096*1024
  if (idx >= M_ * 1024) return;
  int pm = idx >> 10, k = idx & 1023;
  int g = (pm >> 4) & 3;
  int h = (pm >> 7) * 32 + ((pm >> 6) & 1) * 16 + (pm & 15);
  float v = 0.0f;
  if (h < HS) {
    int c = g * HS + h;
    if (k < 512) { if (k < NINP) v = w1[(size_t)c * (NINP * 2) + k * 2 + 0]; }
    else { int j = k - 512; if (j < NINP) v = w1[(size_t)c * (NINP * 2) + j * 2 + 1]; }
  }
  W1q[idx] = (bf16)v;
}

__global__ void repack_w2(const float* __restrict__ w2, bf16* __restrict__ W2q) {
  int idx = blockIdx.x * 256 + threadIdx.x;           // 4096*2048
  if (idx >= M_ * 2048) return;
  int pm = idx >> 11, k = idx & 2047;
  int g = (pm >> 4) & 3;
  int h = (pm >> 7) * 32 + ((pm >> 6) & 1) * 16 + (pm & 15);
  float v = 0.0f;
  if (h < HS) {
    int c = g * HS + h;
    if (k < HP) { if (k < HS) v = w2[(size_t)c * (HS * 2) + k * 2 + 0]; }
    else { int j = k - HP; if (j < HS) v = w2[(size_t)c * (HS * 2) + j * 2 + 1]; }
  }
  W2q[idx] = (bf16)v;
}

// XSg[(1+n)][k]: guard row 0 = zeros (the t==0 tap0 pad); row 1+n = X[b][k][t].
__global__ void build_xs(const float* __restrict__ X, bf16* __restrict__ XSg) {
  int idx = blockIdx.x * 256 + threadIdx.x;           // (NT+1)*512
  if (idx >= (NT + 1) * 512) return;
  int row = idx >> 9, k = idx & 511;
  float v = 0.0f;
  if (row > 0 && k < NINP) {
    int n = row - 1;
    int b = n >> 8, t = n & (T_ - 1);
    v = X[((size_t)b * NINP + k) * T_ + t];
  }
  XSg[idx] = (bf16)v;
}

__global__ void build_hc(const float* __restrict__ hid, const float* __restrict__ cell,
                         bf16* __restrict__ hidp, float* __restrict__ cellp) {
  int idx = blockIdx.x * 256 + threadIdx.x;           // 8*1024
  if (idx >= B_ * HP) return;
  int b = idx >> 10, k = idx & (HP - 1);
  hidp[idx]  = (k < HS) ? (bf16)hid[b * HS + k] : (bf16)0.0f;
  cellp[idx] = (k < HS) ? cell[b * HS + k] : 0.0f;
}

// ---------------- fused GEMM (+gating), 16x16x32 MFMA, tap-shared staging ----------------
// BM=128 x BN=128, 4 waves (64x64), 2 blocks/CU, r5's phase schedule, r7's
// tap-shared Hs (staged once, read by both taps).  r8: GUARD-ROW layout --
// Hs has 65 phys rows; logical row r maps to phys (r>>1)+1, so logical row -1
// (the block boundary, B[n0-1] / hid / zeros) is a REAL row staged per pair at
// its own k-slice by one exec-masked gload_lds (lane<8, 128 B).  This removes
// r7's divergent bv[0] pointer-select, whose mixed-address ds_read_b128 was
// the 5.6x bank-conflict regression (1.29M vs 229K).  All lo-tap reads now use
// one uniform formula.  7 gloads/stage -> vmcnt(7).  Boundary-row slot map:
// phys slot s holds k8=((s+1)&7)&3; read slot (quad+3)&7 -> k8=quad (verified).
// Schedule per pair: ph-lo {reads; BAR; lgkm0+SB; setprio 16xMFMA; BAR},
// ph-hi {reads; lgkm0+SB; BAR(all reads of buf done); stage(p+2); vmcnt(7);
// SB; setprio 16xMFMA; BAR}.  vmcnt never 0 in steady state.

template <bool GATED>
__global__ __launch_bounds__(256, 2) void gemm_step(
    const bf16* __restrict__ A,      // W2q [4096][2048] or W1q [4096][1024] packed-m
    const bf16* __restrict__ Bsrc,   // gated: Hprev [NT][1024]; plain: XSg+512 [NT][512]
    const bf16* __restrict__ hidp,   // [B_][HP]
    const bf16* __restrict__ CbIn,   // gated: CbP [NT][4096] packed-m
    bf16* __restrict__ CbOut,        // plain: write CbP
    const float* __restrict__ b2,
    const bf16* __restrict__ ctprev, // [HP][NT]
    const float* __restrict__ cellp, // [B_][HP]
    bf16* __restrict__ ctnew,        // [HP][NT]
    bf16* __restrict__ Hnew,         // [NT][HP]
    int KH, int BS) {                // KH = K/2 (1024 or 512); BS = B row stride
  __shared__ bf16 SMF[2 * BUFE];     // 49408 B -> 2 blocks/CU

  const int tid = threadIdx.x;
  const int lane = tid & 63;
  const int w = tid >> 6;            // 0..3
  const int mh = w >> 1, nh = w & 1; // wave tile (mh*64, nh*64)
  const int quad = lane >> 4, col = lane & 15;
  const int K = KH * 2;

  // XCD swizzle over 512 blocks (r0-proven)
  const int L = blockIdx.y * gridDim.x + blockIdx.x;
  const int bm = (L & 7) * 4 + (L >> 7);           // 0..31 (128-pm blocks)
  const int n0 = ((L >> 3) & 15) * 128;

  // ---- gated: step-invariant conv1 contribution -> registers ----
  bf16x4 cb0[4], cb1[4], cb2[4], cb3[4];
  if (GATED) {
#pragma unroll
    for (int nt = 0; nt < 4; ++nt) {
      const int n = n0 + nh * 64 + nt * 16 + col;
      const size_t cb = (size_t)n * 4096 + (size_t)(bm * 128 + mh * 64) + quad * 4;
      cb0[nt] = *(const bf16x4*)&CbIn[cb + 0];
      cb1[nt] = *(const bf16x4*)&CbIn[cb + 16];
      cb2[nt] = *(const bf16x4*)&CbIn[cb + 32];
      cb3[nt] = *(const bf16x4*)&CbIn[cb + 48];
    }
  }

  // ---- per-lane fragment-read constants (swizzled layout, flat offsets) ----
  const int colh = col >> 1;
  const int slotA = ((quad + 4 * (col & 1) + (colh & 7)) & 7) * 8;
  const int baseA   = (mh * 32 + colh) * 64 + slotA;          // in Alo/Ahi region
  const int baseBhi = HSB + 64 + (nh * 32 + colh) * 64 + slotA;
  // lo-tap bases, per nt, fully uniform via guard row: phys row = (r>>1)+1
  int baseLo[4];
#pragma unroll
  for (int nt = 0; nt < 4; ++nt) {
    const int r = nh * 64 + nt * 16 + col - 1;     // -1 only at nh==0,nt==0,col==0
    const int pr = r >> 1;                         // arithmetic shift: -1 -> -1
    baseLo[nt] = HSB + (pr + 1) * 64 + (((quad + 4 * (r & 1) + (pr & 7)) & 7) * 8);
  }

  // ---- per-thread DMA source pointers via inverse swizzle ----
  const bf16* paLo[2];
  const bf16* pbs[2];
#pragma unroll
  for (int l = 0; l < 2; ++l) {
    const int f = l * 256 + tid;
    const int pr = f >> 3, sl = f & 7;
    const int u = (sl - (pr & 7)) & 7;
    const int r = 2 * pr + (u >> 2), k8 = u & 3;
    paLo[l] = A + (size_t)(bm * 128 + r) * K + k8 * 8;
    pbs[l]  = Bsrc + (size_t)(n0 + r) * BS + k8 * 8;
  }
  // boundary-row source (step-invariant): logical row n0-1
  //   n0%256==0: gated -> hid row; plain -> zero guard row (Bsrc - BS)
  const bf16* zsrc = GATED ? (hidp + (size_t)(n0 >> 8) * HP) : (Bsrc - BS);
  const bf16* pbm1 = ((n0 & 255) == 0) ? zsrc : (Bsrc + (size_t)(n0 - 1) * BS);
  // lane l<8 writes phys slot l of the boundary row; slot l holds k8=((l+1)&7)&3
  const bf16* pbm1l = pbm1 + (((lane + 1) & 7) & 3) * 8;

  f32x4 acc[4][4];
#pragma unroll
  for (int i = 0; i < 4; ++i)
#pragma unroll
    for (int j = 0; j < 4; ++j) acc[i][j] = (f32x4){0.f, 0.f, 0.f, 0.f};

  auto stage = [&](int buf, int p2) {              // 7 x gload_lds per thread
    const int bufo = buf * BUFE;
#pragma unroll
    for (int l = 0; l < 2; ++l) {
      const int d = (l * 256 + w * 64) * 8;
      async_copy16(&SMF[bufo + ALO + d],      paLo[l] + p2 * 32);
      async_copy16(&SMF[bufo + AHI + d],      paLo[l] + KH + p2 * 32);
      async_copy16(&SMF[bufo + HSB + 64 + d], pbs[l] + p2 * 32);
    }
    if (lane < 8) async_copy16(&SMF[bufo + HSB], pbm1l + p2 * 32);
  };

  const int NP = KH >> 5;            // 32 (gated) or 16 (plain), even

  auto kpair = [&](int p2, int buf) {
    const int bufo = buf * BUFE;
    // ---------- phase LO (tap0: W-lo x B[n-1]) ----------
    {
      bf16x8 av[4], bv[4];
#pragma unroll
      for (int mt = 0; mt < 4; ++mt)
        av[mt] = *(const bf16x8*)&SMF[bufo + ALO + baseA + mt * 512];
#pragma unroll
      for (int nt = 0; nt < 4; ++nt)
        bv[nt] = *(const bf16x8*)&SMF[bufo + baseLo[nt]];
      __builtin_amdgcn_s_barrier();
      asm volatile("s_waitcnt lgkmcnt(0)" ::: "memory");
      __builtin_amdgcn_sched_barrier(0);
      __builtin_amdgcn_s_setprio(1);
#pragma unroll
      for (int mt = 0; mt < 4; ++mt)
#pragma unroll
        for (int nt = 0; nt < 4; ++nt)
          acc[mt][nt] = __builtin_amdgcn_mfma_f32_16x16x32_bf16(av[mt], bv[nt], acc[mt][nt], 0, 0, 0);
      __builtin_amdgcn_s_setprio(0);
      __builtin_amdgcn_s_barrier();
    }
    // ---------- phase HI (tap1: W-hi x B[n]) ----------
    {
      bf16x8 av[4], bv[4];
#pragma unroll
      for (int mt = 0; mt < 4; ++mt)
        av[mt] = *(const bf16x8*)&SMF[bufo + AHI + baseA + mt * 512];
#pragma unroll
      for (int nt = 0; nt < 4; ++nt)
        bv[nt] = *(const bf16x8*)&SMF[bufo + baseBhi + nt * 512];
      asm volatile("s_waitcnt lgkmcnt(0)" ::: "memory");  // my reads in regs
      __builtin_amdgcn_sched_barrier(0);
      __builtin_amdgcn_s_barrier();                // ALL reads of buf done
      if (p2 + 2 < NP) {
        stage(buf, p2 + 2);                        // overwrite this buf
        asm volatile("s_waitcnt vmcnt(7)" ::: "memory");  // pair p2+1 resident
      } else {
        asm volatile("s_waitcnt vmcnt(0)" ::: "memory");
      }
      __builtin_amdgcn_sched_barrier(0);
      __builtin_amdgcn_s_setprio(1);
#pragma unroll
      for (int mt = 0; mt < 4; ++mt)
#pragma unroll
        for (int nt = 0; nt < 4; ++nt)
          acc[mt][nt] = __builtin_amdgcn_mfma_f32_16x16x32_bf16(av[mt], bv[nt], acc[mt][nt], 0, 0, 0);
      __builtin_amdgcn_s_setprio(0);
      __builtin_amdgcn_s_barrier();
    }
  };

  // ---- prologue: first two pairs (each stages its own boundary slice) ----
  stage(0, 0);
  stage(1, 1);
  __syncthreads();                   // drain everything; pairs 0,1 ready

  for (int p = 0; p < NP; p += 2) {
    kpair(p, 0);
    kpair(p + 1, 1);
  }
  __syncthreads();                   // drain for epilogue overlay

  if (!GATED) {
    // epilogue: pack C block [128 n][128 pm] via LDS overlay (32 KB of SMF)
    bf16 (*Csh)[128] = (bf16(*)[128])&SMF[0];
#pragma unroll
    for (int mt = 0; mt < 4; ++mt) {        // mt = gate
#pragma unroll
      for (int nt = 0; nt < 4; ++nt) {
        const int nloc = nh * 64 + nt * 16 + col;
        bf16x4 v;
#pragma unroll
        for (int j = 0; j < 4; ++j) {
          const int h = bm * 32 + mh * 16 + quad * 4 + j;
          const float bias = (h < HS) ? b2[mt * HS + h] : 0.0f;
          v[j] = (bf16)(acc[mt][nt][j] + bias);
        }
        *(bf16x4*)&Csh[nloc][mh * 64 + mt * 16 + quad * 4] = v;
      }
    }
    __syncthreads();
#pragma unroll
    for (int i2 = 0; i2 < 8; ++i2) {
      const int idx = i2 * 256 + tid;       // 128 rows x 16 chunks of 16B
      const int rrow = idx >> 4, off = idx & 15;
      *(u32x4*)&CbOut[(size_t)(n0 + rrow) * 4096 + bm * 128 + off * 8] =
          *(const u32x4*)&Csh[rrow][off * 8];
    }
  } else {
    bf16 (*Hsh)[32] = (bf16(*)[32])&SMF[0];   // [128 n][32 h] = 8 KB
#pragma unroll
    for (int nt = 0; nt < 4; ++nt) {
      const int nloc = nh * 64 + nt * 16 + col;
      const int n = n0 + nloc;
      const int b = n >> 8;
      const int t = n & (T_ - 1);
      bf16x4 hv;
#pragma unroll
      for (int j = 0; j < 4; ++j) {
        const int h = bm * 32 + mh * 16 + quad * 4 + j;
        const float ci = acc[0][nt][j] + (float)cb0[nt][j];
        const float co = acc[1][nt][j] + (float)cb1[nt][j];
        const float cg = acc[2][nt][j] + (float)cb2[nt][j];
        const float cf = acc[3][nt][j] + (float)cb3[nt][j];
        const float ctold = (t == 0) ? cellp[b * HP + h]
                                     : (float)ctprev[(size_t)h * NT + (n - 1)];
        const float cn = sigm(cf) * ctold + sigm(ci) * tanhf(cg);
        ctnew[(size_t)h * NT + n] = (bf16)cn;
        hv[j] = (bf16)(sigm(co) * tanhf(cn));
      }
      *(bf16x4*)&Hsh[nloc][mh * 16 + quad * 4] = hv;
    }
    __syncthreads();
#pragma unroll
    for (int i2 = 0; i2 < 2; ++i2) {
      const int idx = i2 * 256 + tid;       // 128 rows x 4 chunks of 16B
      const int rrow = idx >> 2, off = idx & 3;
      *(u32x4*)&Hnew[(size_t)(n0 + rrow) * HP + bm * 32 + off * 8] =
          *(const u32x4*)&Hsh[rrow][off * 8];
    }
  }
}

// ---------------- output kernels (fp32 out) ----------------

__global__ void aux_kernel(const bf16* __restrict__ H, float* __restrict__ out, int s) {
  int idx = blockIdx.x * 256 + threadIdx.x;  // 8*256*100
  if (idx >= NT * 100) return;
  int n = idx / 100;
  int o = (idx % 100) * 4;
  int b = n >> 8, t = n & (T_ - 1);
  bf16x4 v = *(const bf16x4*)&H[(size_t)n * HP + 600 + o];
  f32x4 f = {(float)v[0], (float)v[1], (float)v[2], (float)v[3]};
  *(f32x4*)&out[AUX_OFF + ((size_t)((b * 2 + s) * T_ + t)) * 400 + o] = f;
}

__global__ void final_kernel(const bf16* __restrict__ H, const bf16* __restrict__ ct,
                             float* __restrict__ out) {
  int idx = blockIdx.x * 256 + threadIdx.x;
  if (idx < NT * 100) {
    int n = idx / 100;
    int o = (idx % 100) * 4;
    int b = n >> 8, t = n & (T_ - 1);
    bf16x4 v = *(const bf16x4*)&H[(size_t)n * HP + 600 + o];
    f32x4 f = {(float)v[0], (float)v[1], (float)v[2], (float)v[3]};
    *(f32x4*)&out[(size_t)n * 400 + o] = f;  // out_main [b][t][400]
    *(f32x4*)&out[AUX_OFF + ((size_t)((b * 2 + 1) * T_ + t)) * 400 + o] = f;
  } else {
    int j = idx - NT * 100;
    if (j < 8000) {
      int b = j / 1000, h = j % 1000;
      out[HT_OFF + j] = (float)H[(size_t)(b * T_ + 255) * HP + h];
    } else if (j < 16000) {
      int jj = j - 8000;
      int b = jj / 1000, h = jj % 1000;
      out[CT_OFF + jj] = (float)ct[(size_t)h * NT + b * T_ + 255];
    }
  }
}

// ---------------- launch ----------------

extern "C" void kernel_launch(void* const* d_in, const int* in_sizes, int n_in,
                              void* d_out, int out_size, void* d_ws, size_t ws_size,
                              hipStream_t stream) {
  const float* X    = (const float*)d_in[0];
  const float* hid  = (const float*)d_in[1];
  const float* cell = (const float*)d_in[2];
  const float* w1   = (const float*)d_in[3];
  const float* w2   = (const float*)d_in[4];
  const float* b2   = (const float*)d_in[5];
  float* out = (float*)d_out;

  char* ws = (char*)d_ws;
  size_t off = 0;
  auto alloc = [&](size_t bytes) {
    void* p = ws + off;
    off += (bytes + 255) & ~(size_t)255;
    return p;
  };
  bf16* W2q    = (bf16*)alloc((size_t)M_ * 2048 * 2);   // 16 MB
  bf16* CbP    = (bf16*)alloc((size_t)NT * M_ * 2);     // 16 MB
  bf16* Hb0    = (bf16*)alloc((size_t)NT * HP * 2);     // 4 MB
  bf16* ctb0   = (bf16*)alloc((size_t)HP * NT * 2);     // 4 MB
  bf16* hidp   = (bf16*)alloc((size_t)B_ * HP * 2);
  float* cellp = (float*)alloc((size_t)B_ * HP * 4);
  // Union region: {W1q, XSg} live only until the first GEMM; then {ctb1, Hb1}.
  char* R = (char*)alloc((size_t)12 * 1024 * 1024);     // 12 MB
  bf16* W1q  = (bf16*)R;                                // 8 MB
  bf16* XSg  = (bf16*)(R + (size_t)8 * 1024 * 1024);    // (NT+1)*512*2 = 2.1 MB
  bf16* ctb1 = (bf16*)R;                                // 4 MB
  bf16* Hb1  = (bf16*)(R + (size_t)4 * 1024 * 1024);    // 4 MB

  bf16* Hb[2]  = {Hb0, Hb1};
  bf16* ctb[2] = {ctb0, ctb1};

  hipMemsetAsync(Hb[0], 0, (size_t)NT * HP * 2, stream);
  hipMemsetAsync(ctb[0], 0, (size_t)HP * NT * 2, stream);

  repack_w1<<<(M_ * 1024) / 256, 256, 0, stream>>>(w1, W1q);
  repack_w2<<<(M_ * 2048) / 256, 256, 0, stream>>>(w2, W2q);
  build_xs<<<((NT + 1) * 512) / 256, 256, 0, stream>>>(X, XSg);
  build_hc<<<(B_ * HP) / 256, 256, 0, stream>>>(hid, cell, hidp, cellp);

  dim3 grid(NT / 128, M_ / 128);  // 16 x 32 = 512 blocks, 2/CU (~49.5 KB LDS)
  gemm_step<false><<<grid, 256, 0, stream>>>(W1q, XSg + 512, nullptr, nullptr, CbP, b2,
                                             nullptr, nullptr, nullptr, nullptr,
                                             512, 512);
  for (int i = 0; i < 40; ++i) {
    int p = i & 1;
    gemm_step<true><<<grid, 256, 0, stream>>>(W2q, Hb[p], hidp, CbP, nullptr, nullptr,
                                              ctb[p], cellp, ctb[p ^ 1], Hb[p ^ 1],
                                              1024, 1024);
    if (i == 19) aux_kernel<<<800, 256, 0, stream>>>(Hb[p ^ 1], out, 0);
  }
  final_kernel<<<(NT * 100 + 16000 + 255) / 256, 256, 0, stream>>>(Hb[0], ctb[0], out);
}